// Round 12
// baseline (618.399 us; speedup 1.0000x reference)
//
#include <hip/hip_runtime.h>

#define NGRAPH 100
#define NPER   1000
#define NNODES 100000
#define NEDGES 1600000
#define EPG    16000   // edges per graph

typedef float v2f __attribute__((ext_vector_type(2)));

// DPP-based add of lane (lane ^ pattern) within a 16-lane row; VALU latency.
template <int CTRL>
__device__ __forceinline__ float dpp_add(float x) {
    int yi = __builtin_amdgcn_update_dpp(0, __float_as_int(x), CTRL, 0xF, 0xF, true);
    return x + __int_as_float(yi);
}
#define DPP_XOR1 0xB1   // quad_perm [1,0,3,2]
#define DPP_XOR2 0x4E   // quad_perm [2,3,0,1]
#define DPP_HMIR 0x141  // row_half_mirror (xor-4 equivalent after quad sums)
#define DPP_MIR  0x140  // row_mirror      (xor-8 equivalent after half sums)

// ==================== utility: zero count + g_acc in one launch ============
__global__ __launch_bounds__(256) void zero2_k(int* __restrict__ count,
                                               float* __restrict__ g_acc) {
    int i = blockIdx.x * 256 + threadIdx.x;
    if (i < NNODES) count[i] = 0;
    if (i < NGRAPH * 96) g_acc[i] = 0.f;
}

// ==================== counting sort of edges by DST ====================
__global__ __launch_bounds__(256) void hist_k(const int* __restrict__ dst,
                                              int* __restrict__ count) {
    int e = blockIdx.x * 256 + threadIdx.x;
    if (e < NEDGES) atomicAdd(&count[dst[e]], 1);
}

__global__ __launch_bounds__(1024) void scan_k(const int* __restrict__ count,
                                               int* __restrict__ offs,
                                               int* __restrict__ cursor) {
    __shared__ int sc[1024];
    int t = threadIdx.x, g = blockIdx.x;
    int v = (t < NPER) ? count[g * NPER + t] : 0;
    sc[t] = v;
    __syncthreads();
    for (int s = 1; s < 1024; s <<= 1) {
        int add = (t >= s) ? sc[t - s] : 0;
        __syncthreads();
        sc[t] += add;
        __syncthreads();
    }
    if (t < NPER) {
        int start = g * EPG + sc[t] - v;   // exclusive
        offs[g * NPER + t]   = start;
        cursor[g * NPER + t] = start;
    }
}

// stores pre-scaled indices: {src*32, etype*32, elabel*32, etype*4}
__global__ __launch_bounds__(256) void scatter_k(
    const int* __restrict__ src, const int* __restrict__ dst,
    const int* __restrict__ et, const int* __restrict__ el,
    int* __restrict__ cursor, int4* __restrict__ sorted) {
    int e = blockIdx.x * 256 + threadIdx.x;
    if (e >= NEDGES) return;
    int d = dst[e];
    int p = atomicAdd(&cursor[d], 1);
    int et_ = et[e];
    sorted[p] = make_int4(src[e] * 32, et_ * 32, el[e] * 32, et_ * 4);
}

// ==================== node projections: channel-sliced + rel tables ========
__global__ __launch_bounds__(256, 4) void node_k(
    const float* __restrict__ h, const float* __restrict__ basis_l,
    const float* __restrict__ selfw_l, const float* __restrict__ Aw_l,
    const float* __restrict__ Ab_l, const float* __restrict__ attn_tab,
    float* __restrict__ xproj, float* __restrict__ psrc,
    float* __restrict__ pdst, float* __restrict__ selfp,
    float* __restrict__ t1, float* __restrict__ t2)
{
    const int y = blockIdx.y;
    if (y == 6) {   // rel tables: r = bid*4 + wave, 64 threads per r
        int r = blockIdx.x * 4 + (threadIdx.x >> 6);
        if (r >= 200) return;
        int t = threadIdx.x & 63;
        int o = t & 31;
        bool second = t >= 32;
        const float* at = attn_tab + r * 32;
        const float* W  = Aw_l + (second ? 96*32 : 64*32);
        float acc = second ? 0.f : Ab_l[o];
        #pragma unroll 8
        for (int d = 0; d < 32; d++) acc += at[d] * W[d*32 + o];
        (second ? t2 : t1)[r*32 + o] = acc;
        return;
    }

    __shared__ float w_s[4096];
    if (y < 4) {
        const float4* b4 = (const float4*)basis_l;   // 1024 float4
        float4* w4 = (float4*)w_s;
        for (int k = threadIdx.x; k < 1024; k += 256) w4[k] = b4[k];
    } else {
        const float4* a4 = (const float4*)Aw_l;      // 512 float4 (rows 0..63)
        const float4* s4 = (const float4*)selfw_l;   // 256 float4
        float4* w4 = (float4*)w_s;
        for (int k = threadIdx.x; k < 768; k += 256)
            w4[k] = (k < 512) ? a4[k] : s4[k - 512];
    }
    __syncthreads();

    int n = blockIdx.x * 256 + threadIdx.x;
    if (n >= NNODES) return;

    float hreg[32];
    {
        const float4* hp = (const float4*)(h + n * 32);
        #pragma unroll
        for (int k = 0; k < 8; k++) {
            float4 v = hp[k];
            hreg[4*k+0]=v.x; hreg[4*k+1]=v.y; hreg[4*k+2]=v.z; hreg[4*k+3]=v.w;
        }
    }

    if (y < 4) {
        float* xout = xproj + n * 128 + y * 32;
        #pragma unroll 1
        for (int ocl = 0; ocl < 2; ocl++) {
            const int oc = y * 2 + ocl;
            float4 p[4];
            #pragma unroll 1
            for (int b = 0; b < 4; b++) {
                const float* wb = w_s + b * 1024 + oc * 4;
                float4 a = {0.f,0.f,0.f,0.f};
                #pragma unroll 4
                for (int d = 0; d < 32; d++) {
                    float4 wv = *(const float4*)(wb + d * 32);
                    a.x = fmaf(hreg[d], wv.x, a.x);
                    a.y = fmaf(hreg[d], wv.y, a.y);
                    a.z = fmaf(hreg[d], wv.z, a.z);
                    a.w = fmaf(hreg[d], wv.w, a.w);
                }
                p[b] = a;
            }
            // pair-pack: [pair][b][j], 64B contiguous
            float* o = xout + ocl * 16;
            *(float4*)(o +  0) = make_float4(p[0].x, p[0].y, p[1].x, p[1].y);
            *(float4*)(o +  4) = make_float4(p[2].x, p[2].y, p[3].x, p[3].y);
            *(float4*)(o +  8) = make_float4(p[0].z, p[0].w, p[1].z, p[1].w);
            *(float4*)(o + 12) = make_float4(p[2].z, p[2].w, p[3].z, p[3].w);
        }
    } else {
        const int oc0 = (y - 4) * 4;
        #pragma unroll 1
        for (int m = 0; m < 3; m++) {
            const float* wbase = w_s + (m < 2 ? m * 1024 : 2048);
            float* outp = (m == 0 ? psrc : m == 1 ? pdst : selfp);
            float4 r[4];
            #pragma unroll 1
            for (int ocl = 0; ocl < 4; ocl++) {
                const float* wb = wbase + (oc0 + ocl) * 4;
                float4 a = {0.f,0.f,0.f,0.f};
                #pragma unroll 4
                for (int d = 0; d < 32; d++) {
                    float4 wv = *(const float4*)(wb + d * 32);
                    a.x = fmaf(hreg[d], wv.x, a.x);
                    a.y = fmaf(hreg[d], wv.y, a.y);
                    a.z = fmaf(hreg[d], wv.z, a.z);
                    a.w = fmaf(hreg[d], wv.w, a.w);
                }
                r[ocl] = a;
            }
            float* o = outp + n * 32 + oc0 * 4;   // 64B line
            *(float4*)(o +  0) = r[0];
            *(float4*)(o +  4) = r[1];
            *(float4*)(o +  8) = r[2];
            *(float4*)(o + 12) = r[3];
        }
    }
}

// ==================== CSR edge kernel: 16 lanes/edge, DPP reduce ===========
// wave = 1 node, 4 edge-slots of 16 lanes, 2 channels/lane (packed f32).
// In-loop reduce is 4 DPP steps (VALU latency) instead of shfl_xor
// (LDS-pipe ~30-40cyc each) -- R10 showed the kernel is chain-latency-bound.
// sorted[] record for iteration i+1 is loaded before iteration i's softmax.
__global__ __launch_bounds__(256) void edge_csr_k(
    const int4* __restrict__ sorted, const int* __restrict__ offs,
    const float* __restrict__ psrc, const float* __restrict__ pdst,
    const float* __restrict__ t1,   const float* __restrict__ t2,
    const float* __restrict__ xproj, const float* __restrict__ selfp,
    const float* __restrict__ wcomp_l,
    const float* __restrict__ Bw, const float* __restrict__ Bb,
    float* __restrict__ h_next)
{
    // XCD-bijective swizzle: 25000 blocks, 25000 % 8 == 0.
    const int CPX = 25000 / 8;
    int bid = (int)blockIdx.x;
    bid = (bid % 8) * CPX + bid / 8;

    const int wib  = threadIdx.x >> 6;   // wave in block: 0..3
    const int lane = threadIdx.x & 63;
    const int grp  = lane >> 4;          // edge slot 0..3
    const int ci   = lane & 15;          // channel pair
    const int c2   = ci * 2;
    const int n    = bid * 4 + wib;      // dst node

    const int start = offs[n];
    const int end   = (n == NNODES - 1) ? NEDGES : offs[n + 1];
    const v2f bw = *(const v2f*)(Bw + c2);
    const float bb = Bb[0];
    const v2f pd = *(const v2f*)(pdst + n * 32 + c2);

    int e = start + grp;
    int4 ed = sorted[(e < end) ? e : start];
    bool valid = (e < end);

    v2f acc = {0.f, 0.f};
    for (int e0 = start; e0 < end; e0 += 4) {
        // current edge record
        int4 cur = ed;
        bool cv = valid;
        // issue next record load early (independent of this iter's chain)
        int en = e + 4;
        valid = (en < end);
        ed = sorted[valid ? en : start];
        e = en;

        v2f ps = *(const v2f*)(psrc + cur.x + c2);
        v2f ta = *(const v2f*)(t1 + cur.y + c2);
        v2f tb = *(const v2f*)(t2 + cur.z + c2);
        float4 c = *(const float4*)(wcomp_l + cur.w);
        const float4* xp = (const float4*)(xproj + cur.x * 4 + ci * 8);
        float4 x01 = xp[0];   // pair-packed [b0j0 b0j1 b1j0 b1j1]
        float4 x23 = xp[1];   // [b2j0 b2j1 b3j0 b3j1]

        v2f z = ps + pd + ta + tb;
        z.x = fmaxf(z.x, 0.f);
        z.y = fmaxf(z.y, 0.f);
        float d = fmaf(z.x, bw.x, z.y * bw.y);
        d = dpp_add<DPP_XOR1>(d);
        d = dpp_add<DPP_XOR2>(d);
        d = dpp_add<DPP_HMIR>(d);
        d = dpp_add<DPP_MIR>(d);
        float a = __builtin_amdgcn_rcpf(1.f + __expf(-(d + bb)));
        a = cv ? a : 0.f;

        v2f b0 = {x01.x, x01.y};
        v2f b1 = {x01.z, x01.w};
        v2f b2 = {x23.x, x23.y};
        v2f b3 = {x23.z, x23.w};
        v2f m = c.x * b0 + c.y * b1 + c.z * b2 + c.w * b3;
        acc += a * m;
    }
    // reduce the 4 edge-slots (once per node; shfl ok off the hot chain)
    acc.x += __shfl_xor(acc.x, 16);
    acc.y += __shfl_xor(acc.y, 16);
    acc.x += __shfl_xor(acc.x, 32);
    acc.y += __shfl_xor(acc.y, 32);
    if (lane < 16) {
        v2f sp = *(const v2f*)(selfp + n * 32 + c2);
        v2f hv;
        hv.x = fmaxf(acc.x + sp.x, 0.f);
        hv.y = fmaxf(acc.y + sp.y, 0.f);
        *(v2f*)(h_next + n * 32 + c2) = hv;
    }
}

// ==================== per-graph mean (8 slices) + head/tail (y=8) ==========
__global__ __launch_bounds__(256) void mean_ht_k(
    const float* __restrict__ h, const int* __restrict__ head_ids,
    const int* __restrict__ tail_ids, float* __restrict__ g_acc,
    float* __restrict__ head_buf, float* __restrict__ tail_buf, int l)
{
    int g  = blockIdx.x;
    int sl = blockIdx.y;
    int i  = threadIdx.x & 31;
    if (sl == 8) {
        if (threadIdx.x < 32)
            head_buf[g*96 + l*32 + i] = h[head_ids[g]*32 + i];
        else if (threadIdx.x < 64)
            tail_buf[g*96 + l*32 + i] = h[tail_ids[g]*32 + i];
        return;
    }
    int sub = threadIdx.x >> 5;
    float acc = 0.f;
    for (int k = sub; k < 125; k += 8)
        acc += h[(g*NPER + sl*125 + k)*32 + i];
    __shared__ float red[8][32];
    red[sub][i] = acc;
    __syncthreads();
    if (threadIdx.x < 32) {
        float s2 = 0.f;
        #pragma unroll
        for (int k = 0; k < 8; k++) s2 += red[k][threadIdx.x];
        atomicAdd(&g_acc[g*96 + l*32 + threadIdx.x], s2 * (1.0f/NPER));
    }
}

// ==================== final readout ====================
__global__ __launch_bounds__(64) void readout_k(
    const float* __restrict__ g_acc, const float* __restrict__ head_buf,
    const float* __restrict__ tail_buf, const float* __restrict__ rel_tab,
    const int* __restrict__ rel_labels, const float* __restrict__ fc_w,
    const float* __restrict__ fc_b, float* __restrict__ out)
{
    int g = blockIdx.x;
    int t = threadIdx.x;
    float s = 0.f;
    for (int idx = t; idx < 320; idx += 64) {
        float v;
        if (idx < 96)       v = g_acc[g*96 + idx];
        else if (idx < 192) v = head_buf[g*96 + idx - 96];
        else if (idx < 288) v = tail_buf[g*96 + idx - 192];
        else                v = rel_tab[rel_labels[g]*32 + (idx - 288)];
        s += v * fc_w[idx];
    }
    s += __shfl_xor(s, 1, 64);
    s += __shfl_xor(s, 2, 64);
    s += __shfl_xor(s, 4, 64);
    s += __shfl_xor(s, 8, 64);
    s += __shfl_xor(s, 16, 64);
    s += __shfl_xor(s, 32, 64);
    if (t == 0) out[g] = s + fc_b[0];
}

extern "C" void kernel_launch(void* const* d_in, const int* in_sizes, int n_in,
                              void* d_out, int out_size, void* d_ws, size_t ws_size,
                              hipStream_t stream) {
    const float* feat        = (const float*)d_in[0];
    const float* basis       = (const float*)d_in[1];   // [3,4,32,32]
    const float* w_comp      = (const float*)d_in[2];   // [3,200,4]
    const float* self_loop_w = (const float*)d_in[3];   // [3,32,32]
    const float* A_w         = (const float*)d_in[4];   // [3,128,32]
    const float* A_b         = (const float*)d_in[5];   // [3,32]
    const float* B_w         = (const float*)d_in[6];   // [3,32,1]
    const float* B_b         = (const float*)d_in[7];   // [3,1]
    const float* attn_tab    = (const float*)d_in[8];   // [200,32]
    const float* rel_tab     = (const float*)d_in[9];   // [200,32]
    const float* fc_w        = (const float*)d_in[10];  // [320,1]
    const float* fc_b        = (const float*)d_in[11];  // [1]
    const int* src        = (const int*)d_in[12];
    const int* dst        = (const int*)d_in[13];
    const int* etype      = (const int*)d_in[14];
    const int* elabel     = (const int*)d_in[15];
    const int* head_ids   = (const int*)d_in[17];
    const int* tail_ids   = (const int*)d_in[18];
    const int* rel_labels = (const int*)d_in[19];

    float* ws = (float*)d_ws;
    size_t off = 0;
    float* h0    = ws + off; off += (size_t)NNODES * 32;
    float* h1    = ws + off; off += (size_t)NNODES * 32;
    float* xproj = ws + off; off += (size_t)NNODES * 128;
    float* psrc  = ws + off; off += (size_t)NNODES * 32;
    float* pdst  = ws + off; off += (size_t)NNODES * 32;
    float* selfp = ws + off; off += (size_t)NNODES * 32;
    float* t1    = ws + off; off += 200 * 32;
    float* t2    = ws + off; off += 200 * 32;
    float* g_acc    = ws + off; off += NGRAPH * 96;
    float* head_buf = ws + off; off += NGRAPH * 96;
    float* tail_buf = ws + off; off += NGRAPH * 96;
    int* count  = (int*)(ws + off); off += NNODES;
    int* offs   = (int*)(ws + off); off += NNODES;
    int* cursor = (int*)(ws + off); off += NNODES;
    off = (off + 3) & ~(size_t)3;               // 16 B align
    int4* sorted = (int4*)(ws + off); off += (size_t)NEDGES * 4;

    // ---- one-time per call: CSR by dst + zero mean accumulator ----
    zero2_k<<<(NNODES + 255)/256, 256, 0, stream>>>(count, g_acc);
    hist_k<<<(NEDGES + 255)/256, 256, 0, stream>>>(dst, count);
    scan_k<<<NGRAPH, 1024, 0, stream>>>(count, offs, cursor);
    scatter_k<<<(NEDGES + 255)/256, 256, 0, stream>>>(src, dst, etype, elabel,
                                                      cursor, sorted);

    const float* hcur = feat;
    float* hbufs[2] = { h0, h1 };
    for (int l = 0; l < 3; l++) {
        dim3 ngrid((NNODES + 255)/256, 7);
        node_k<<<ngrid, 256, 0, stream>>>(
            hcur, basis + (size_t)l*4096, self_loop_w + (size_t)l*1024,
            A_w + (size_t)l*4096, A_b + (size_t)l*32, attn_tab,
            xproj, psrc, pdst, selfp, t1, t2);
        float* hn = hbufs[l & 1];
        edge_csr_k<<<NNODES/4, 256, 0, stream>>>(
            sorted, offs, psrc, pdst, t1, t2, xproj, selfp,
            w_comp + (size_t)l*800, B_w + (size_t)l*32, B_b + l, hn);
        dim3 mgrid(NGRAPH, 9);
        mean_ht_k<<<mgrid, 256, 0, stream>>>(
            hn, head_ids, tail_ids, g_acc, head_buf, tail_buf, l);
        hcur = hn;
    }
    readout_k<<<NGRAPH, 64, 0, stream>>>(
        g_acc, head_buf, tail_buf, rel_tab, rel_labels, fc_w, fc_b, (float*)d_out);
}